// Round 1
// baseline (558.041 us; speedup 1.0000x reference)
//
#include <hip/hip_runtime.h>

// ---------------- constants ----------------
#define HEADS 6
#define DIM 192
#define DH 32
#define PW 144            // tokens per window
#define WN 960            // windows
#define MWD 15            // MW
#define NTOK (WN*PW)      // 138240
#define SCALE 0.17677669529663687f

typedef __attribute__((ext_vector_type(8))) short bf16x8;
typedef __attribute__((ext_vector_type(4))) short bf16x4;
typedef __attribute__((ext_vector_type(4))) float f32x4;

#define MFMA16(a,b,c) __builtin_amdgcn_mfma_f32_16x16x32_bf16(a,b,c,0,0,0)

__device__ __forceinline__ unsigned short f2bf(float f) {
    unsigned int u = __builtin_bit_cast(unsigned int, f);
    u += 0x7fffu + ((u >> 16) & 1u);
    return (unsigned short)(u >> 16);
}
__device__ __forceinline__ float bf2f(unsigned short s) {
    unsigned int u = ((unsigned int)s) << 16;
    return __builtin_bit_cast(float, u);
}

// ---------------- P1: weight transpose + bf16 ----------------
// wqkvT[n][k] = wqkv[k][n]  (576x192), wprojT[n][k] = wproj[k][n] (192x192)
__global__ void prep_weights(const float* __restrict__ wqkv,
                             const float* __restrict__ wproj,
                             unsigned short* __restrict__ wqkvT,
                             unsigned short* __restrict__ wprojT) {
    int t = blockIdx.x * 256 + threadIdx.x;     // 147456 total
    if (t < 576 * 192) {
        int n = t / 192, k = t % 192;
        wqkvT[t] = f2bf(wqkv[k * 576 + n]);
    } else {
        int t2 = t - 576 * 192;                 // < 36864
        int n = t2 / 192, k = t2 % 192;
        wprojT[t2] = f2bf(wproj[k * 192 + n]);
    }
}

// ---------------- P2: dense bias [wt][h][i][j] bf16 ----------------
__global__ void prep_bias(const float* __restrict__ table,
                          unsigned short* __restrict__ bias_d) {
    int t = blockIdx.x * 256 + threadIdx.x;     // 7,962,624 total (exact)
    int j = t % 144;
    int i = (t / 144) % 144;
    int h = (t / 20736) % 6;
    int wt = t / 124416;
    int z1 = i / 72, h1 = (i / 12) % 6, w1 = i % 12;
    int z2 = j / 72, h2 = (j / 12) % 6, w2 = j % 12;
    int pos = (z1 + 2 * z2) * 828 + (h1 + 6 * h2) * 23 + (w1 - w2 + 11);
    bias_d[t] = f2bf(table[pos * 384 + wt * 6 + h]);
}

// ---------------- K1: qkv = x @ w_qkv, scatter to q/k/vT (bf16) ----------------
// grid (6, 2880), block 192.  BM=48 rows, BN=96 cols, K=192.
__global__ __launch_bounds__(192) void qkv_gemm(
        const float* __restrict__ x, const unsigned short* __restrict__ wqkvT,
        unsigned short* __restrict__ qb, unsigned short* __restrict__ kb,
        unsigned short* __restrict__ vtb) {
    __shared__ unsigned short A[48 * 200];   // pad 192->200 (400B = 25*16B)
    __shared__ unsigned short Bt[96 * 200];
    int nblk = blockIdx.x;   // 0..5
    int mblk = blockIdx.y;   // 0..2879
    int tid = threadIdx.x;

    // stage A: 48x192 fp32 -> bf16 (2304 float4 chunks)
    const float* xp = x + mblk * (48 * 192);
    #pragma unroll
    for (int it = 0; it < 12; ++it) {
        int g = tid + it * 192;
        int row = g / 48, c4 = g % 48;
        f32x4 v = *(const f32x4*)(xp + row * 192 + c4 * 4);
        bf16x4 o;
        o[0] = (short)f2bf(v[0]); o[1] = (short)f2bf(v[1]);
        o[2] = (short)f2bf(v[2]); o[3] = (short)f2bf(v[3]);
        *(bf16x4*)&A[row * 200 + c4 * 4] = o;
    }
    // stage Bt: rows [nblk*96, +96) of wqkvT (96x192 bf16 = 2304 8-elem chunks)
    const unsigned short* wp = wqkvT + nblk * (96 * 192);
    #pragma unroll
    for (int it = 0; it < 12; ++it) {
        int g = tid + it * 192;
        int row = g / 24, c8 = (g % 24) * 8;
        *(bf16x8*)&Bt[row * 200 + c8] = *(const bf16x8*)(wp + row * 192 + c8);
    }
    __syncthreads();

    int lane = tid & 63, wv = tid >> 6;
    int l16 = lane & 15, quad = lane >> 4;
    f32x4 acc[6];
    #pragma unroll
    for (int i = 0; i < 6; ++i) acc[i] = (f32x4){0.f, 0.f, 0.f, 0.f};

    #pragma unroll
    for (int kc = 0; kc < 6; ++kc) {
        bf16x8 af = *(const bf16x8*)&A[(wv * 16 + l16) * 200 + kc * 32 + quad * 8];
        #pragma unroll
        for (int nt = 0; nt < 6; ++nt) {
            bf16x8 bfr = *(const bf16x8*)&Bt[(nt * 16 + l16) * 200 + kc * 32 + quad * 8];
            acc[nt] = MFMA16(af, bfr, acc[nt]);
        }
    }

    // epilogue: token = mblk*48 + wv*16 + quad*4 + r ; col c = nblk*96 + nt*16 + l16
    int win = mblk / 3;                       // 48 | 144
    int pbase = (mblk % 3) * 48 + wv * 16 + quad * 4;
    #pragma unroll
    for (int nt = 0; nt < 6; ++nt) {
        int c0 = nblk * 96 + nt * 16;
        int which = c0 / 192;
        int head = (c0 % 192) / 32;
        int d = (c0 % 32) + l16;
        if (which == 0) {
            int base = ((win * 6 + head) * 144) * 32 + d;
            #pragma unroll
            for (int r = 0; r < 4; ++r) qb[base + (pbase + r) * 32] = f2bf(acc[nt][r]);
        } else if (which == 1) {
            int base = ((win * 6 + head) * 144) * 32 + d;
            #pragma unroll
            for (int r = 0; r < 4; ++r) kb[base + (pbase + r) * 32] = f2bf(acc[nt][r]);
        } else {
            int base = ((win * 6 + head) * 32 + d) * 144 + pbase;   // transposed
            bf16x4 o;
            #pragma unroll
            for (int r = 0; r < 4; ++r) o[r] = (short)f2bf(acc[nt][r]);
            *(bf16x4*)&vtb[base] = o;
        }
    }
}

// ---------------- K2: attention per (window, head) ----------------
// grid 5760, block 192 (3 waves); each wave does 3 row-tiles of 16.
__global__ __launch_bounds__(192) void attn(
        const unsigned short* __restrict__ qb, const unsigned short* __restrict__ kb,
        const unsigned short* __restrict__ vtb, const unsigned short* __restrict__ bias_d,
        const float* __restrict__ mask, unsigned short* __restrict__ Ob) {
    __shared__ unsigned short Q[144 * 40];    // 32 -> pad 40 (80B = 5*16B)
    __shared__ unsigned short Kl[144 * 40];
    __shared__ unsigned short Vt[32 * 152];   // 144 -> pad 152 (304B = 19*16B)
    __shared__ unsigned short Pl[3 * 16 * 168];  // per-wave 16x168 (144 + 16 zero pad + pad)

    int bx = blockIdx.x;
    int win = bx / 6, h = bx % 6;
    int wt = win / MWD;
    int tid = threadIdx.x;
    int lane = tid & 63, wv = tid >> 6;
    int l16 = lane & 15, quad = lane >> 4;

    int qoff = (win * 6 + h) * (144 * 32);
    // stage Q, K (576 chunks of 8 each), Vt (576 chunks)
    #pragma unroll
    for (int it = 0; it < 3; ++it) {
        int c = tid + it * 192;
        int row = c >> 2, c8 = (c & 3) * 8;
        *(bf16x8*)&Q[row * 40 + c8]  = *(const bf16x8*)(qb + qoff + c * 8);
        *(bf16x8*)&Kl[row * 40 + c8] = *(const bf16x8*)(kb + qoff + c * 8);
        int vr = c / 18, vc = (c % 18) * 8;
        *(bf16x8*)&Vt[vr * 152 + vc] = *(const bf16x8*)(vtb + qoff + c * 8);
    }
    // zero the P pad columns [144,160) of this wave's tile
    {
        int row = lane >> 2, ch = lane & 3;
        *(bf16x4*)&Pl[wv * 2688 + row * 168 + 144 + ch * 4] = (bf16x4){0, 0, 0, 0};
    }
    __syncthreads();

    const float* maskp = mask + win * 20736;
    const unsigned short* biasp = bias_d + (wt * 6 + h) * 20736;
    const f32x4 z = {0.f, 0.f, 0.f, 0.f};

    for (int rt = 0; rt < 3; ++rt) {
        int i0 = (wv * 3 + rt) * 16;
        bf16x8 aq = *(const bf16x8*)&Q[(i0 + l16) * 40 + quad * 8];
        f32x4 s[9];
        #pragma unroll
        for (int ct = 0; ct < 9; ++ct) {
            bf16x8 bk = *(const bf16x8*)&Kl[(ct * 16 + l16) * 40 + quad * 8];
            s[ct] = MFMA16(aq, bk, z);
        }
        // scale + bias + mask
        #pragma unroll
        for (int ct = 0; ct < 9; ++ct) {
            int j = ct * 16 + l16;
            #pragma unroll
            for (int r = 0; r < 4; ++r) {
                int i = i0 + quad * 4 + r;
                float b = bf2f(biasp[i * 144 + j]);
                float mk = maskp[i * 144 + j];
                s[ct][r] = s[ct][r] * SCALE + b + mk;
            }
        }
        // softmax per row (row = quad*4+r; 144 values live in 9 regs x 16 lanes)
        #pragma unroll
        for (int r = 0; r < 4; ++r) {
            float mx = s[0][r];
            #pragma unroll
            for (int ct = 1; ct < 9; ++ct) mx = fmaxf(mx, s[ct][r]);
            #pragma unroll
            for (int off = 1; off < 16; off <<= 1) mx = fmaxf(mx, __shfl_xor(mx, off, 64));
            float sum = 0.f;
            #pragma unroll
            for (int ct = 0; ct < 9; ++ct) { float e = __expf(s[ct][r] - mx); s[ct][r] = e; sum += e; }
            #pragma unroll
            for (int off = 1; off < 16; off <<= 1) sum += __shfl_xor(sum, off, 64);
            float inv = 1.0f / sum;
            #pragma unroll
            for (int ct = 0; ct < 9; ++ct) s[ct][r] *= inv;
        }
        // write P tile (bf16) to LDS
        int pb = wv * 2688;
        #pragma unroll
        for (int ct = 0; ct < 9; ++ct) {
            #pragma unroll
            for (int r = 0; r < 4; ++r)
                Pl[pb + (quad * 4 + r) * 168 + ct * 16 + l16] = f2bf(s[ct][r]);
        }
        // O = P @ V   (K = 160, pad cols are zero)
        f32x4 o0 = z, o1 = z;
        #pragma unroll
        for (int kc = 0; kc < 5; ++kc) {
            bf16x8 ap = *(const bf16x8*)&Pl[pb + l16 * 168 + kc * 32 + quad * 8];
            bf16x8 b0 = *(const bf16x8*)&Vt[l16 * 152 + kc * 32 + quad * 8];
            bf16x8 b1 = *(const bf16x8*)&Vt[(16 + l16) * 152 + kc * 32 + quad * 8];
            o0 = MFMA16(ap, b0, o0);
            o1 = MFMA16(ap, b1, o1);
        }
        // write O (bf16) [token][h*32 + d]
        #pragma unroll
        for (int r = 0; r < 4; ++r) {
            int i = i0 + quad * 4 + r;
            int ob = (win * 144 + i) * 192 + h * 32 + l16;
            Ob[ob] = f2bf(o0[r]);
            Ob[ob + 16] = f2bf(o1[r]);
        }
    }
}

// ---------------- K3: out = O @ w_proj + b_proj (fp32 out) ----------------
// grid (2, 2880), block 192.  BM=48, BN=96, K=192.
__global__ __launch_bounds__(192) void out_gemm(
        const unsigned short* __restrict__ Ob, const unsigned short* __restrict__ wprojT,
        const float* __restrict__ bproj, float* __restrict__ out) {
    __shared__ unsigned short A[48 * 200];
    __shared__ unsigned short Bt[96 * 200];
    int nblk = blockIdx.x;
    int mblk = blockIdx.y;
    int tid = threadIdx.x;

    const unsigned short* op = Ob + mblk * (48 * 192);
    #pragma unroll
    for (int it = 0; it < 6; ++it) {
        int c = tid + it * 192;              // 1152 chunks
        int row = c / 24, c8 = (c % 24) * 8;
        *(bf16x8*)&A[row * 200 + c8] = *(const bf16x8*)(op + c * 8);
    }
    const unsigned short* wp = wprojT + nblk * (96 * 192);
    #pragma unroll
    for (int it = 0; it < 12; ++it) {
        int c = tid + it * 192;              // 2304 chunks
        int row = c / 24, c8 = (c % 24) * 8;
        *(bf16x8*)&Bt[row * 200 + c8] = *(const bf16x8*)(wp + c * 8);
    }
    __syncthreads();

    int lane = tid & 63, wv = tid >> 6;
    int l16 = lane & 15, quad = lane >> 4;
    f32x4 acc[6];
    #pragma unroll
    for (int i = 0; i < 6; ++i) acc[i] = (f32x4){0.f, 0.f, 0.f, 0.f};
    #pragma unroll
    for (int kc = 0; kc < 6; ++kc) {
        bf16x8 af = *(const bf16x8*)&A[(wv * 16 + l16) * 200 + kc * 32 + quad * 8];
        #pragma unroll
        for (int nt = 0; nt < 6; ++nt) {
            bf16x8 bfr = *(const bf16x8*)&Bt[(nt * 16 + l16) * 200 + kc * 32 + quad * 8];
            acc[nt] = MFMA16(af, bfr, acc[nt]);
        }
    }
    int token0 = mblk * 48 + wv * 16 + quad * 4;
    #pragma unroll
    for (int nt = 0; nt < 6; ++nt) {
        int c = nblk * 96 + nt * 16 + l16;
        float bp = bproj[c];
        #pragma unroll
        for (int r = 0; r < 4; ++r)
            out[(token0 + r) * 192 + c] = acc[nt][r] + bp;
    }
}

// ---------------- launch ----------------
extern "C" void kernel_launch(void* const* d_in, const int* in_sizes, int n_in,
                              void* d_out, int out_size, void* d_ws, size_t ws_size,
                              hipStream_t stream) {
    const float* x     = (const float*)d_in[0];
    const float* mask  = (const float*)d_in[1];
    const float* wqkv  = (const float*)d_in[2];
    const float* wproj = (const float*)d_in[3];
    const float* bproj = (const float*)d_in[4];
    const float* btab  = (const float*)d_in[5];
    float* out = (float*)d_out;

    char* ws = (char*)d_ws;
    // ws layout (bytes):
    unsigned short* qb     = (unsigned short*)(ws + 0);            // 53,084,160
    unsigned short* kb     = (unsigned short*)(ws + 53084160);     // 53,084,160
    unsigned short* vtb    = (unsigned short*)(ws + 106168320);    // 53,084,160
    unsigned short* Ob     = (unsigned short*)(ws + 159252480);    // 53,084,160
    unsigned short* bias_d = (unsigned short*)(ws + 212336640);    // 15,925,248
    unsigned short* wqkvT  = (unsigned short*)(ws + 228261888);    //    221,184
    unsigned short* wprojT = (unsigned short*)(ws + 228483072);    //     73,728
    // total: 228,556,800 bytes

    prep_weights<<<576, 256, 0, stream>>>(wqkv, wproj, wqkvT, wprojT);
    prep_bias<<<31104, 256, 0, stream>>>(btab, bias_d);
    qkv_gemm<<<dim3(6, 2880), 192, 0, stream>>>(x, wqkvT, qb, kb, vtb);
    attn<<<5760, 192, 0, stream>>>(qb, kb, vtb, bias_d, mask, Ob);
    out_gemm<<<dim3(2, 2880), 192, 0, stream>>>(Ob, wprojT, bproj, out);
}

// Round 3
// 486.024 us; speedup vs baseline: 1.1482x; 1.1482x over previous
//
#include <hip/hip_runtime.h>

// ---------------- constants ----------------
#define HEADS 6
#define DIM 192
#define DH 32
#define PW 144            // tokens per window
#define WN 960            // windows
#define MWD 15            // MW
#define NTOK (WN*PW)      // 138240
#define SCALE 0.17677669529663687f

typedef __attribute__((ext_vector_type(8))) short bf16x8;
typedef __attribute__((ext_vector_type(4))) short bf16x4;
typedef __attribute__((ext_vector_type(4))) float f32x4;

#define MFMA16(a,b,c) __builtin_amdgcn_mfma_f32_16x16x32_bf16(a,b,c,0,0,0)

__device__ __forceinline__ unsigned short f2bf(float f) {
    unsigned int u = __builtin_bit_cast(unsigned int, f);
    u += 0x7fffu + ((u >> 16) & 1u);
    return (unsigned short)(u >> 16);
}
__device__ __forceinline__ float bf2f(unsigned short s) {
    unsigned int u = ((unsigned int)s) << 16;
    return __builtin_bit_cast(float, u);
}

// ---------------- P1: weight transpose + bf16 ----------------
__global__ void prep_weights(const float* __restrict__ wqkv,
                             const float* __restrict__ wproj,
                             unsigned short* __restrict__ wqkvT,
                             unsigned short* __restrict__ wprojT) {
    int t = blockIdx.x * 256 + threadIdx.x;     // 147456 total
    if (t < 576 * 192) {
        int n = t / 192, k = t % 192;
        wqkvT[t] = f2bf(wqkv[k * 576 + n]);
    } else {
        int t2 = t - 576 * 192;                 // < 36864
        int n = t2 / 192, k = t2 % 192;
        wprojT[t2] = f2bf(wproj[k * 192 + n]);
    }
}

// ---------------- P2: dense bias [wt][h][i][j] bf16 ----------------
__global__ void prep_bias(const float* __restrict__ table,
                          unsigned short* __restrict__ bias_d) {
    int t = blockIdx.x * 256 + threadIdx.x;     // 7,962,624 total (exact)
    int j = t % 144;
    int i = (t / 144) % 144;
    int h = (t / 20736) % 6;
    int wt = t / 124416;
    int z1 = i / 72, h1 = (i / 12) % 6, w1 = i % 12;
    int z2 = j / 72, h2 = (j / 12) % 6, w2 = j % 12;
    int pos = (z1 + 2 * z2) * 828 + (h1 + 6 * h2) * 23 + (w1 - w2 + 11);
    bias_d[t] = f2bf(table[pos * 384 + wt * 6 + h]);
}

// ---------------- P3: cast x fp32 -> bf16 ----------------
// 26,542,080 elems = 3,317,760 chunks of 8; grid 12960 x 256 exact.
__global__ __launch_bounds__(256) void prep_cast(const float* __restrict__ x,
                                                 unsigned short* __restrict__ xb) {
    long long c = (long long)blockIdx.x * 256 + threadIdx.x;
    const float* p = x + c * 8;
    f32x4 v0 = *(const f32x4*)p;
    f32x4 v1 = *(const f32x4*)(p + 4);
    bf16x8 o;
    o[0] = (short)f2bf(v0[0]); o[1] = (short)f2bf(v0[1]);
    o[2] = (short)f2bf(v0[2]); o[3] = (short)f2bf(v0[3]);
    o[4] = (short)f2bf(v1[0]); o[5] = (short)f2bf(v1[1]);
    o[6] = (short)f2bf(v1[2]); o[7] = (short)f2bf(v1[3]);
    *(bf16x8*)(xb + c * 8) = o;
}

// ---------------- K1: qkv = xb @ w_qkv, scatter to q/k/vT (bf16) ----------------
// grid 12960 (swizzled: 2160 mtiles x 6 nblk), block 256 (4 waves).
// BM=64 rows, BN=96 cols, K=192. LDS = 64*200*2 + 96*200*2 = 64,000 B.
__global__ __launch_bounds__(256) void qkv_gemm(
        const unsigned short* __restrict__ xb, const unsigned short* __restrict__ wqkvT,
        unsigned short* __restrict__ qb, unsigned short* __restrict__ kb,
        unsigned short* __restrict__ vtb) {
    __shared__ unsigned short A[64 * 200];
    __shared__ unsigned short Bt[96 * 200];
    int bid = blockIdx.x;
    int r8 = bid & 7, s = bid >> 3;          // s < 1620
    int nblk = s % 6;                        // 0..5
    int mtile = r8 * 270 + s / 6;            // 0..2159  (all nblks of one mtile on one XCD)
    int tid = threadIdx.x;

    // stage A: 64x192 bf16 = 1536 16B chunks
    const unsigned short* xp = xb + (long long)mtile * (64 * 192);
    #pragma unroll
    for (int it = 0; it < 6; ++it) {
        int c = tid + it * 256;
        int row = c / 24, c8 = (c % 24) * 8;
        *(bf16x8*)&A[row * 200 + c8] = *(const bf16x8*)(xp + c * 8);
    }
    // stage Bt: rows [nblk*96, +96) of wqkvT = 2304 chunks
    const unsigned short* wp = wqkvT + nblk * (96 * 192);
    #pragma unroll
    for (int it = 0; it < 9; ++it) {
        int c = tid + it * 256;
        int row = c / 24, c8 = (c % 24) * 8;
        *(bf16x8*)&Bt[row * 200 + c8] = *(const bf16x8*)(wp + c * 8);
    }
    __syncthreads();

    int lane = tid & 63, wv = tid >> 6;
    int l16 = lane & 15, quad = lane >> 4;
    f32x4 acc[6];
    #pragma unroll
    for (int i = 0; i < 6; ++i) acc[i] = (f32x4){0.f, 0.f, 0.f, 0.f};

    #pragma unroll
    for (int kc = 0; kc < 6; ++kc) {
        bf16x8 af = *(const bf16x8*)&A[(wv * 16 + l16) * 200 + kc * 32 + quad * 8];
        #pragma unroll
        for (int ct = 0; ct < 6; ++ct) {
            bf16x8 bfr = *(const bf16x8*)&Bt[(ct * 16 + l16) * 200 + kc * 32 + quad * 8];
            acc[ct] = MFMA16(af, bfr, acc[ct]);
        }
    }

    // epilogue
    int token0 = mtile * 64 + wv * 16 + quad * 4;
    int win = token0 / 144;
    int p0 = token0 - win * 144;             // p0..p0+3 stay in-window (both %4==0)
    #pragma unroll
    for (int ct = 0; ct < 6; ++ct) {
        int c0 = nblk * 96 + ct * 16;
        int which = c0 / 192;
        int head = (c0 % 192) / 32;
        int d = (c0 % 32) + l16;
        if (which == 0) {
            int base = ((win * 6 + head) * 144 + p0) * 32 + d;
            #pragma unroll
            for (int r = 0; r < 4; ++r) qb[base + r * 32] = f2bf(acc[ct][r]);
        } else if (which == 1) {
            int base = ((win * 6 + head) * 144 + p0) * 32 + d;
            #pragma unroll
            for (int r = 0; r < 4; ++r) kb[base + r * 32] = f2bf(acc[ct][r]);
        } else {
            int base = ((win * 6 + head) * 32 + d) * 144 + p0;   // transposed
            bf16x4 o;
            #pragma unroll
            for (int r = 0; r < 4; ++r) o[r] = (short)f2bf(acc[ct][r]);
            *(bf16x4*)&vtb[base] = o;
        }
    }
}

// ---------------- K2: attention per (window, head) ----------------
// grid 5760 swizzled so all 6 heads of a window share an XCD; block 192 (3 waves).
// Vt stride 160: PV-MFMA K range is [0,160) (144 real + 16 zero pad), fragment
// offsets reach exactly 160 -> all reads in-row, in-bounds. Pad cols [144,160)
// of BOTH P (A operand) and Vt (B operand) are explicitly zeroed: an
// uninitialized-LDS read here (round-1/2 layout) made 0*Inf = NaN.
__global__ __launch_bounds__(192) void attn(
        const unsigned short* __restrict__ qb, const unsigned short* __restrict__ kb,
        const unsigned short* __restrict__ vtb, const unsigned short* __restrict__ bias_d,
        const float* __restrict__ mask, unsigned short* __restrict__ Ob) {
    __shared__ unsigned short Q[144 * 40];
    __shared__ unsigned short Kl[144 * 40];
    __shared__ unsigned short Vt[32 * 160];
    __shared__ unsigned short Pl[3 * 16 * 168];

    int bx = blockIdx.x;
    int r8 = bx & 7, s = bx >> 3;            // s < 720
    int h = s % 6;
    int win = r8 * 120 + s / 6;              // all heads of win -> XCD r8, adjacent in time
    int wt = win / MWD;
    int tid = threadIdx.x;
    int lane = tid & 63, wv = tid >> 6;
    int l16 = lane & 15, quad = lane >> 4;

    int qoff = (win * 6 + h) * (144 * 32);
    #pragma unroll
    for (int it = 0; it < 3; ++it) {
        int c = tid + it * 192;
        int row = c >> 2, c8 = (c & 3) * 8;
        *(bf16x8*)&Q[row * 40 + c8]  = *(const bf16x8*)(qb + qoff + c * 8);
        *(bf16x8*)&Kl[row * 40 + c8] = *(const bf16x8*)(kb + qoff + c * 8);
        int vr = c / 18, vc = (c % 18) * 8;
        *(bf16x8*)&Vt[vr * 160 + vc] = *(const bf16x8*)(vtb + qoff + c * 8);
    }
    // zero P pad cols [144,160) of this wave's tile
    {
        int row = lane >> 2, ch = lane & 3;
        *(bf16x4*)&Pl[wv * 2688 + row * 168 + 144 + ch * 4] = (bf16x4){0, 0, 0, 0};
    }
    // zero Vt pad cols [144,160) of all 32 rows (512 shorts = 64 chunks of 8)
    if (tid < 64) {
        int row = tid >> 1, off = 144 + (tid & 1) * 8;
        *(bf16x8*)&Vt[row * 160 + off] = (bf16x8){0, 0, 0, 0, 0, 0, 0, 0};
    }
    __syncthreads();

    const float* maskp = mask + win * 20736;
    const unsigned short* biasp = bias_d + (wt * 6 + h) * 20736;
    const f32x4 z = {0.f, 0.f, 0.f, 0.f};

    for (int rt = 0; rt < 3; ++rt) {
        int i0 = (wv * 3 + rt) * 16;
        bf16x8 aq = *(const bf16x8*)&Q[(i0 + l16) * 40 + quad * 8];
        f32x4 sreg[9];
        #pragma unroll
        for (int ct = 0; ct < 9; ++ct) {
            bf16x8 bk = *(const bf16x8*)&Kl[(ct * 16 + l16) * 40 + quad * 8];
            sreg[ct] = MFMA16(aq, bk, z);
        }
        #pragma unroll
        for (int ct = 0; ct < 9; ++ct) {
            int j = ct * 16 + l16;
            #pragma unroll
            for (int r = 0; r < 4; ++r) {
                int i = i0 + quad * 4 + r;
                float b = bf2f(biasp[i * 144 + j]);
                float mk = maskp[i * 144 + j];
                sreg[ct][r] = sreg[ct][r] * SCALE + b + mk;
            }
        }
        #pragma unroll
        for (int r = 0; r < 4; ++r) {
            float mx = sreg[0][r];
            #pragma unroll
            for (int ct = 1; ct < 9; ++ct) mx = fmaxf(mx, sreg[ct][r]);
            #pragma unroll
            for (int off = 1; off < 16; off <<= 1) mx = fmaxf(mx, __shfl_xor(mx, off, 64));
            float sum = 0.f;
            #pragma unroll
            for (int ct = 0; ct < 9; ++ct) { float e = __expf(sreg[ct][r] - mx); sreg[ct][r] = e; sum += e; }
            #pragma unroll
            for (int off = 1; off < 16; off <<= 1) sum += __shfl_xor(sum, off, 64);
            float inv = 1.0f / sum;
            #pragma unroll
            for (int ct = 0; ct < 9; ++ct) sreg[ct][r] *= inv;
        }
        int pb = wv * 2688;
        #pragma unroll
        for (int ct = 0; ct < 9; ++ct) {
            #pragma unroll
            for (int r = 0; r < 4; ++r)
                Pl[pb + (quad * 4 + r) * 168 + ct * 16 + l16] = f2bf(sreg[ct][r]);
        }
        f32x4 o0 = z, o1 = z;
        #pragma unroll
        for (int kc = 0; kc < 5; ++kc) {
            bf16x8 ap = *(const bf16x8*)&Pl[pb + l16 * 168 + kc * 32 + quad * 8];
            bf16x8 b0 = *(const bf16x8*)&Vt[l16 * 160 + kc * 32 + quad * 8];
            bf16x8 b1 = *(const bf16x8*)&Vt[(16 + l16) * 160 + kc * 32 + quad * 8];
            o0 = MFMA16(ap, b0, o0);
            o1 = MFMA16(ap, b1, o1);
        }
        #pragma unroll
        for (int r = 0; r < 4; ++r) {
            int i = i0 + quad * 4 + r;
            int ob = (win * 144 + i) * 192 + h * 32 + l16;
            Ob[ob] = f2bf(o0[r]);
            Ob[ob + 16] = f2bf(o1[r]);
        }
    }
}

// ---------------- K3: out = O @ w_proj + b_proj (fp32 out) ----------------
// grid 4320 (swizzled: 2160 mtiles x 2 nblk), block 256. BM=64, BN=96, K=192.
__global__ __launch_bounds__(256) void out_gemm(
        const unsigned short* __restrict__ Ob, const unsigned short* __restrict__ wprojT,
        const float* __restrict__ bproj, float* __restrict__ out) {
    __shared__ unsigned short A[64 * 200];
    __shared__ unsigned short Bt[96 * 200];
    int bid = blockIdx.x;
    int r8 = bid & 7, s = bid >> 3;          // s < 540
    int nblk = s % 2;
    int mtile = r8 * 270 + s / 2;            // 0..2159
    int tid = threadIdx.x;

    const unsigned short* op = Ob + (long long)mtile * (64 * 192);
    #pragma unroll
    for (int it = 0; it < 6; ++it) {
        int c = tid + it * 256;
        int row = c / 24, c8 = (c % 24) * 8;
        *(bf16x8*)&A[row * 200 + c8] = *(const bf16x8*)(op + c * 8);
    }
    const unsigned short* wp = wprojT + nblk * (96 * 192);
    #pragma unroll
    for (int it = 0; it < 9; ++it) {
        int c = tid + it * 256;
        int row = c / 24, c8 = (c % 24) * 8;
        *(bf16x8*)&Bt[row * 200 + c8] = *(const bf16x8*)(wp + c * 8);
    }
    __syncthreads();

    int lane = tid & 63, wv = tid >> 6;
    int l16 = lane & 15, quad = lane >> 4;
    f32x4 acc[6];
    #pragma unroll
    for (int i = 0; i < 6; ++i) acc[i] = (f32x4){0.f, 0.f, 0.f, 0.f};
    #pragma unroll
    for (int kc = 0; kc < 6; ++kc) {
        bf16x8 af = *(const bf16x8*)&A[(wv * 16 + l16) * 200 + kc * 32 + quad * 8];
        #pragma unroll
        for (int ct = 0; ct < 6; ++ct) {
            bf16x8 bfr = *(const bf16x8*)&Bt[(ct * 16 + l16) * 200 + kc * 32 + quad * 8];
            acc[ct] = MFMA16(af, bfr, acc[ct]);
        }
    }
    int token0 = mtile * 64 + wv * 16 + quad * 4;
    #pragma unroll
    for (int ct = 0; ct < 6; ++ct) {
        int c = nblk * 96 + ct * 16 + l16;
        float bp = bproj[c];
        #pragma unroll
        for (int r = 0; r < 4; ++r)
            out[(token0 + r) * 192 + c] = acc[ct][r] + bp;
    }
}

// ---------------- launch ----------------
extern "C" void kernel_launch(void* const* d_in, const int* in_sizes, int n_in,
                              void* d_out, int out_size, void* d_ws, size_t ws_size,
                              hipStream_t stream) {
    const float* x     = (const float*)d_in[0];
    const float* mask  = (const float*)d_in[1];
    const float* wqkv  = (const float*)d_in[2];
    const float* wproj = (const float*)d_in[3];
    const float* bproj = (const float*)d_in[4];
    const float* btab  = (const float*)d_in[5];
    float* out = (float*)d_out;

    char* ws = (char*)d_ws;
    // ws layout (bytes):
    unsigned short* xb     = (unsigned short*)(ws + 0);            // 53,084,160 (union w/ Ob)
    unsigned short* Ob     = (unsigned short*)(ws + 0);            // x dead before attn writes O
    unsigned short* qb     = (unsigned short*)(ws + 53084160);     // 53,084,160
    unsigned short* kb     = (unsigned short*)(ws + 106168320);    // 53,084,160
    unsigned short* vtb    = (unsigned short*)(ws + 159252480);    // 53,084,160
    unsigned short* bias_d = (unsigned short*)(ws + 212336640);    // 15,925,248
    unsigned short* wqkvT  = (unsigned short*)(ws + 228261888);    //    221,184
    unsigned short* wprojT = (unsigned short*)(ws + 228483072);    //     73,728
    // total: 228,556,800 bytes

    prep_weights<<<576, 256, 0, stream>>>(wqkv, wproj, wqkvT, wprojT);
    prep_bias<<<31104, 256, 0, stream>>>(btab, bias_d);
    prep_cast<<<12960, 256, 0, stream>>>(x, xb);
    qkv_gemm<<<12960, 256, 0, stream>>>(xb, wqkvT, qb, kb, vtb);
    attn<<<5760, 192, 0, stream>>>(qb, kb, vtb, bias_d, mask, Ob);
    out_gemm<<<4320, 256, 0, stream>>>(Ob, wprojT, bproj, out);
}